// Round 6
// baseline (41048.828 us; speedup 1.0000x reference)
//
#include <hip/hip_runtime.h>
#include <math.h>

// NSE recurrent model, B=32, L=1024, K=256.
// Step t: reader LSTM -> hr_t ; scores s_l = hr_t . mem_l ; softmax z ;
// m_rt = sum z_l mem_l ; writer gates = [hr,m_rt]@Wf + hw@wWh + bf  (composer folded:
// Wf = cW@wWx, bf = cb@wWx + wb) ; mem update deferred to next step's attn pass.
//
// R6: GEMVs batched over groups of 8 batches (weight traffic 160 -> 20 MB/step).
//   k_attn (1024 blk) ; k_wrf (128 blk: 64 batched writer + 64 batched reader t+1).

#define Bb 32
#define LL 1024
#define KK 256
#define N4K 1024   // 4*K
#define N2K 512    // 2*K
#define NC 32      // L-chunks per batch row in attention kernel
#define RC 32      // rows per chunk = LL/NC
#define BG 8       // batches per GEMV block

__device__ __forceinline__ float sigf(float v) { return 1.0f / (1.0f + __expf(-v)); }

// ---------------- init: mem <- x, zero LSTM states ----------------
__global__ void k_init(const float* __restrict__ x, float* __restrict__ mem,
                       float* __restrict__ states /* 8 * B*K floats */) {
    long long n = (long long)Bb * LL * KK;
    for (long long i = (long long)blockIdx.x * blockDim.x + threadIdx.x; i < n;
         i += (long long)gridDim.x * blockDim.x)
        mem[i] = x[i];
    for (int i = blockIdx.x * blockDim.x + threadIdx.x; i < 8 * Bb * KK;
         i += gridDim.x * blockDim.x)
        states[i] = 0.0f;
}

// ---------------- pre: Wf = cW @ wWx (512x1024), bf = cb @ wWx + wb ----------------
__global__ __launch_bounds__(256) void k_pre(
    const float* __restrict__ cW, const float* __restrict__ cb,
    const float* __restrict__ wWx, const float* __restrict__ wb,
    float* __restrict__ Wf, float* __restrict__ bf) {
    int tid = threadIdx.x;
    __shared__ float srow[N2K];
    if (blockIdx.x < N2K) {
        int kr = blockIdx.x;
        srow[tid] = cW[(size_t)kr * N2K + tid];
        srow[KK + tid] = cW[(size_t)kr * N2K + KK + tid];
        __syncthreads();
#pragma unroll
        for (int rep = 0; rep < 4; rep++) {
            int col = rep * 256 + tid;
            float a = 0.f;
#pragma unroll 4
            for (int c = 0; c < N2K; c++) a += srow[c] * wWx[(size_t)c * N4K + col];
            Wf[(size_t)kr * N4K + col] = a;
        }
    } else {
        int col = (blockIdx.x - N2K) * 256 + tid;
        float a = wb[col];
#pragma unroll 4
        for (int c = 0; c < N2K; c++) a += cb[c] * wWx[(size_t)c * N4K + col];
        bf[col] = a;
    }
}

// ---------------- batched reader LSTM: BG batches, 16 j x 4 gates, 4-way k-split ----
// shin layout: [b][512] = [x(256) | hr(256)]
__device__ __forceinline__ void reader_blk8(
    int bg, int jg, int tid, int t1,
    const float* __restrict__ x, const float* __restrict__ rWx,
    const float* __restrict__ rWh, const float* __restrict__ rbv,
    const float* __restrict__ hr_in, const float* __restrict__ cr_in,
    float* __restrict__ hr_out, float* __restrict__ cr_out,
    float* shin, float* sred, float* sg) {
#pragma unroll
    for (int b = 0; b < BG; b++) {
        int bglob = bg * BG + b;
        shin[b * N2K + tid] = x[((size_t)bglob * LL + t1) * KK + tid];
        shin[b * N2K + KK + tid] = hr_in[bglob * KK + tid];
    }
    __syncthreads();
    int c64 = tid & 63, ks = tid >> 6;
    int g = c64 >> 4, jq = c64 & 15;
    int col = g * KK + jg * 16 + jq;
    float acc[BG];
    float binit = (ks == 0) ? rbv[col] : 0.f;
#pragma unroll
    for (int b = 0; b < BG; b++) acc[b] = binit;
    int k0 = ks * 128;
    const float* W = (ks < 2) ? (rWx + (size_t)k0 * N4K + col)
                              : (rWh + (size_t)(k0 - KK) * N4K + col);
    for (int kk = 0; kk < 128; kk += 4) {
        float w0 = W[(size_t)(kk + 0) * N4K];
        float w1 = W[(size_t)(kk + 1) * N4K];
        float w2 = W[(size_t)(kk + 2) * N4K];
        float w3 = W[(size_t)(kk + 3) * N4K];
#pragma unroll
        for (int b = 0; b < BG; b++) {
            float4 v = *(const float4*)&shin[b * N2K + k0 + kk];
            acc[b] += w0 * v.x + w1 * v.y + w2 * v.z + w3 * v.w;
        }
    }
#pragma unroll
    for (int b = 0; b < BG; b++) sred[(ks * 64 + c64) * BG + b] = acc[b];
    __syncthreads();
#pragma unroll
    for (int r = 0; r < 2; r++) {
        int idx = tid * 2 + r;
        int cc = idx >> 3, b = idx & 7;
        sg[cc * BG + b] = sred[(0 * 64 + cc) * BG + b] + sred[(1 * 64 + cc) * BG + b] +
                          sred[(2 * 64 + cc) * BG + b] + sred[(3 * 64 + cc) * BG + b];
    }
    __syncthreads();
    if (tid < 16 * BG) {
        int jl = tid >> 3, b = tid & 7;
        int bglob = bg * BG + b;
        int j = jg * 16 + jl;
        float gi = sg[(0 * 16 + jl) * BG + b], gf = sg[(1 * 16 + jl) * BG + b];
        float gG = sg[(2 * 16 + jl) * BG + b], go = sg[(3 * 16 + jl) * BG + b];
        float cn = sigf(gf) * cr_in[bglob * KK + j] + sigf(gi) * tanhf(gG);
        float hn = sigf(go) * tanhf(cn);
        cr_out[bglob * KK + j] = cn;
        hr_out[bglob * KK + j] = hn;
    }
}

__global__ __launch_bounds__(256) void k_rd(
    const float* __restrict__ x, const float* __restrict__ rWx,
    const float* __restrict__ rWh, const float* __restrict__ rbv,
    const float* __restrict__ hr_in, const float* __restrict__ cr_in,
    float* __restrict__ hr_out, float* __restrict__ cr_out, int t) {
    __shared__ float shin[BG * N2K];
    __shared__ float sred[4 * 64 * BG];
    __shared__ float sg[64 * BG];
    reader_blk8(blockIdx.x >> 4, blockIdx.x & 15, threadIdx.x, t, x, rWx, rWh, rbv,
                hr_in, cr_in, hr_out, cr_out, shin, sred, sg);
}

// ---------------- attention: (deferred mem update) + scores + online softmax ----------------
// grid (NC, B), 256 threads = 4 waves; wave handles 8 rows; lane holds K-slice [ln*4, ln*4+4)
__global__ __launch_bounds__(256) void k_attn(
    float* __restrict__ mem, const float* __restrict__ hr,
    float* __restrict__ s, float* __restrict__ partM, float* __restrict__ partS,
    float* __restrict__ partV, const float* __restrict__ hw_prev,
    const float* __restrict__ Mf, const float* __restrict__ Sf, int upd) {
    int c = blockIdx.x, b = blockIdx.y;
    int tid = threadIdx.x, w = tid >> 6, ln = tid & 63;

    float4 h4 = ((const float4*)(hr + b * KK))[ln];
    float4 w4 = make_float4(0.f, 0.f, 0.f, 0.f);
    float Mprev = 0.f, invS = 0.f;
    if (upd) {
        w4 = ((const float4*)(hw_prev + b * KK))[ln];
        Mprev = Mf[b];
        invS = 1.0f / Sf[b];
    }

    float Mw = -INFINITY, Sw = 0.f;
    float4 Vw = make_float4(0.f, 0.f, 0.f, 0.f);
    int l0 = c * RC + w * 8;
#pragma unroll
    for (int i = 0; i < 8; i++) {
        int l = l0 + i;
        float4* vp = (float4*)(mem + ((size_t)(b * LL + l)) * KK) + ln;
        float4 v = *vp;
        if (upd) {
            float z = __expf(s[b * LL + l] - Mprev) * invS;
            float om = 1.0f - z;
            v.x = v.x * om + w4.x * z;
            v.y = v.y * om + w4.y * z;
            v.z = v.z * om + w4.z * z;
            v.w = v.w * om + w4.w * z;
            *vp = v;
        }
        float d = h4.x * v.x + h4.y * v.y + h4.z * v.z + h4.w * v.w;
#pragma unroll
        for (int m = 1; m < 64; m <<= 1) d += __shfl_xor(d, m, 64);
        if (ln == 0) s[b * LL + l] = d;
        float nM = fmaxf(Mw, d);
        float sc = __expf(Mw - nM);
        float e = __expf(d - nM);
        Sw = Sw * sc + e;
        Vw.x = Vw.x * sc + e * v.x;
        Vw.y = Vw.y * sc + e * v.y;
        Vw.z = Vw.z * sc + e * v.z;
        Vw.w = Vw.w * sc + e * v.w;
        Mw = nM;
    }
    __shared__ float sM4[4], sS4[4];
    __shared__ float sV[4][KK];
    sV[w][ln * 4 + 0] = Vw.x;
    sV[w][ln * 4 + 1] = Vw.y;
    sV[w][ln * 4 + 2] = Vw.z;
    sV[w][ln * 4 + 3] = Vw.w;
    if (ln == 0) { sM4[w] = Mw; sS4[w] = Sw; }
    __syncthreads();
    int k = tid;
    float M = fmaxf(fmaxf(sM4[0], sM4[1]), fmaxf(sM4[2], sM4[3]));
    float e0 = __expf(sM4[0] - M), e1 = __expf(sM4[1] - M);
    float e2 = __expf(sM4[2] - M), e3 = __expf(sM4[3] - M);
    float S = e0 * sS4[0] + e1 * sS4[1] + e2 * sS4[2] + e3 * sS4[3];
    float V = e0 * sV[0][k] + e1 * sV[1][k] + e2 * sV[2][k] + e3 * sV[3][k];
    partV[((size_t)(b * NC + c)) * KK + k] = V;
    if (tid == 0) {
        partM[b * NC + c] = M;
        partS[b * NC + c] = S;
    }
}

// ---------------- fused batched writer (blocks 0..63) + batched reader t+1 (64..127) ----
// writer block (bg, jg): softmax-reduce for 8 batches, then 64 gate-cols x 8 batches,
// 4-way k-split over 768 rows: [hr(256)|m_rt(256)]@Wf + hw@wWh, + bf.
// shin layout: [b][768] = [hr | m_rt | hw]
__global__ __launch_bounds__(256) void k_wrf(
    const float* __restrict__ partM, const float* __restrict__ partS,
    const float* __restrict__ partV, const float* __restrict__ hr_cur,
    const float* __restrict__ Wf, const float* __restrict__ bf,
    const float* __restrict__ wWh,
    const float* __restrict__ hw_in, const float* __restrict__ cw_in,
    float* __restrict__ hw_out, float* __restrict__ cw_out,
    float* __restrict__ Mf, float* __restrict__ Sf, float* __restrict__ out, int t,
    const float* __restrict__ x, const float* __restrict__ rWx,
    const float* __restrict__ rWh, const float* __restrict__ rbv,
    const float* __restrict__ hr_in, const float* __restrict__ cr_in,
    float* __restrict__ hr_out, float* __restrict__ cr_out, int do_reader) {
    __shared__ float shin[BG * 768];
    __shared__ float sred[4 * 64 * BG];
    __shared__ float sg[64 * BG];
    __shared__ float sMp[BG * NC], sSp[BG * NC], sEp[BG * NC];
    __shared__ float sMS[BG], sSS[BG];
    int tid = threadIdx.x;
    if (blockIdx.x < 64) {
        int bg = blockIdx.x >> 4, jg = blockIdx.x & 15;
        // ---- load partials (8 batches x 32 chunks)
        {
            int bl = tid >> 5, c = tid & 31;
            sMp[tid] = partM[(bg * BG + bl) * NC + c];
            sSp[tid] = partS[(bg * BG + bl) * NC + c];
        }
        __syncthreads();
        if (tid < BG) {
            float M = -INFINITY;
#pragma unroll
            for (int c = 0; c < NC; c++) M = fmaxf(M, sMp[tid * NC + c]);
            sMS[tid] = M;
        }
        __syncthreads();
        sEp[tid] = __expf(sMp[tid] - sMS[tid >> 5]);
        __syncthreads();
        if (tid < BG) {
            float S = 0.f;
#pragma unroll
            for (int c = 0; c < NC; c++) S += sEp[tid * NC + c] * sSp[tid * NC + c];
            sSS[tid] = S;
            if (jg == 0) { Mf[bg * BG + tid] = sMS[tid]; Sf[bg * BG + tid] = S; }
        }
        __syncthreads();
        // ---- m_rt reduce + stage hr, hw
#pragma unroll
        for (int b = 0; b < BG; b++) {
            int bglob = bg * BG + b;
            float V = 0.f;
            for (int c = 0; c < NC; c++)
                V += sEp[b * NC + c] * partV[((size_t)(bglob * NC + c)) * KK + tid];
            shin[b * 768 + KK + tid] = V / sSS[b];
            shin[b * 768 + tid] = hr_cur[bglob * KK + tid];
            shin[b * 768 + N2K + tid] = hw_in[bglob * KK + tid];
        }
        __syncthreads();
        // ---- batched GEMV: 64 cols x 4 k-splits, 8 batch accumulators
        int c64 = tid & 63, ks = tid >> 6;
        int g = c64 >> 4, jq = c64 & 15;
        int col = g * KK + jg * 16 + jq;
        float acc[BG];
        float binit = (ks == 0) ? bf[col] : 0.f;
#pragma unroll
        for (int b = 0; b < BG; b++) acc[b] = binit;
        int k0 = ks * 192, k1 = k0 + 192;
        int kb = k1 < N2K ? k1 : N2K;
        for (int k = k0; k < kb; k += 4) {
            float w0 = Wf[(size_t)(k + 0) * N4K + col];
            float w1 = Wf[(size_t)(k + 1) * N4K + col];
            float w2 = Wf[(size_t)(k + 2) * N4K + col];
            float w3 = Wf[(size_t)(k + 3) * N4K + col];
#pragma unroll
            for (int b = 0; b < BG; b++) {
                float4 v = *(const float4*)&shin[b * 768 + k];
                acc[b] += w0 * v.x + w1 * v.y + w2 * v.z + w3 * v.w;
            }
        }
        for (int k = (k0 > N2K ? k0 : N2K); k < k1; k += 4) {
            float w0 = wWh[(size_t)(k - N2K + 0) * N4K + col];
            float w1 = wWh[(size_t)(k - N2K + 1) * N4K + col];
            float w2 = wWh[(size_t)(k - N2K + 2) * N4K + col];
            float w3 = wWh[(size_t)(k - N2K + 3) * N4K + col];
#pragma unroll
            for (int b = 0; b < BG; b++) {
                float4 v = *(const float4*)&shin[b * 768 + k];
                acc[b] += w0 * v.x + w1 * v.y + w2 * v.z + w3 * v.w;
            }
        }
#pragma unroll
        for (int b = 0; b < BG; b++) sred[(ks * 64 + c64) * BG + b] = acc[b];
        __syncthreads();
#pragma unroll
        for (int r = 0; r < 2; r++) {
            int idx = tid * 2 + r;
            int cc = idx >> 3, b = idx & 7;
            sg[cc * BG + b] = sred[(0 * 64 + cc) * BG + b] + sred[(1 * 64 + cc) * BG + b] +
                              sred[(2 * 64 + cc) * BG + b] + sred[(3 * 64 + cc) * BG + b];
        }
        __syncthreads();
        if (tid < 16 * BG) {
            int jl = tid >> 3, b = tid & 7;
            int bglob = bg * BG + b;
            int j = jg * 16 + jl;
            float gi = sg[(0 * 16 + jl) * BG + b], gf = sg[(1 * 16 + jl) * BG + b];
            float gG = sg[(2 * 16 + jl) * BG + b], go = sg[(3 * 16 + jl) * BG + b];
            float cn = sigf(gf) * cw_in[bglob * KK + j] + sigf(gi) * tanhf(gG);
            float hn = sigf(go) * tanhf(cn);
            cw_out[bglob * KK + j] = cn;
            hw_out[bglob * KK + j] = hn;
            out[((size_t)bglob * LL + t) * KK + j] = hn;
        }
    } else if (do_reader) {
        int r2 = blockIdx.x - 64;
        reader_blk8(r2 >> 4, r2 & 15, tid, t + 1, x, rWx, rWh, rbv,
                    hr_in, cr_in, hr_out, cr_out, shin, sred, sg);
    }
}

// ---------------- host ----------------
extern "C" void kernel_launch(void* const* d_in, const int* in_sizes, int n_in,
                              void* d_out, int out_size, void* d_ws, size_t ws_size,
                              hipStream_t stream) {
    const float* x   = (const float*)d_in[0];
    const float* rWx = (const float*)d_in[1];
    const float* rWh = (const float*)d_in[2];
    const float* rb  = (const float*)d_in[3];
    const float* wWx = (const float*)d_in[4];
    const float* wWh = (const float*)d_in[5];
    const float* wb  = (const float*)d_in[6];
    const float* cW  = (const float*)d_in[7];
    const float* cb  = (const float*)d_in[8];
    float* out = (float*)d_out;

    float* ws = (float*)d_ws;
    const size_t MEM = (size_t)Bb * LL * KK;  // 8388608
    float* mem = ws;
    float* states = ws + MEM;                 // 8 state buffers, contiguous
    float* hr[2] = {states + 0 * Bb * KK, states + 1 * Bb * KK};
    float* cr[2] = {states + 2 * Bb * KK, states + 3 * Bb * KK};
    float* hw[2] = {states + 4 * Bb * KK, states + 5 * Bb * KK};
    float* cw[2] = {states + 6 * Bb * KK, states + 7 * Bb * KK};
    float* s     = states + 8 * Bb * KK;              // B*L
    float* partM = s + (size_t)Bb * LL;               // B*NC
    float* partS = partM + Bb * NC;                   // B*NC
    float* partV = partS + Bb * NC;                   // B*NC*K
    float* Mf    = partV + (size_t)Bb * NC * KK;      // B
    float* Sf    = Mf + Bb;                           // B
    float* Wf    = Sf + Bb;                           // 512*1024
    float* bf    = Wf + (size_t)N2K * N4K;            // 1024

    k_init<<<4096, 256, 0, stream>>>(x, mem, states);
    k_pre<<<516, 256, 0, stream>>>(cW, cb, wWx, wb, Wf, bf);
    k_rd<<<64, 256, 0, stream>>>(x, rWx, rWh, rb, hr[0], cr[0], hr[1], cr[1], 0);

    for (int t = 0; t < LL; t++) {
        int pi = t & 1;
        int po = (t + 1) & 1;
        k_attn<<<dim3(NC, Bb), 256, 0, stream>>>(mem, hr[po], s, partM, partS, partV,
                                                 hw[pi], Mf, Sf, t > 0 ? 1 : 0);
        k_wrf<<<128, 256, 0, stream>>>(partM, partS, partV, hr[po], Wf, bf, wWh,
                                       hw[pi], cw[pi], hw[po], cw[po], Mf, Sf, out, t,
                                       x, rWx, rWh, rb, hr[po], cr[po], hr[pi], cr[pi],
                                       (t + 1 < LL) ? 1 : 0);
    }
}

// Round 7
// 36288.620 us; speedup vs baseline: 1.1312x; 1.1312x over previous
//
#include <hip/hip_runtime.h>
#include <math.h>

// NSE recurrent model, B=32, L=1024, K=256.
// Step t: reader LSTM -> hr_t ; scores s_l = hr_t . mem_l ; softmax z ;
// m_rt = sum z_l mem_l ; writer gates = [hr,m_rt]@Wf + hw@wWh + bf  (composer folded:
// Wf = cW@wWx, bf = cb@wWx + wb) ; mem update deferred to next step's attn pass.
//
// R7: R5 structure; writer/reader blocks cover 2 col-groups (2 cols/thread, shared
// LDS reads) -> weight traffic halved, k_wrf = 512 blocks (2/CU).

#define Bb 32
#define LL 1024
#define KK 256
#define N4K 1024   // 4*K
#define N2K 512    // 2*K
#define NC 32      // L-chunks per batch row in attention kernel
#define RC 32      // rows per chunk = LL/NC

__device__ __forceinline__ float sigf(float v) { return 1.0f / (1.0f + __expf(-v)); }

// ---------------- init: mem <- x, zero LSTM states ----------------
__global__ void k_init(const float* __restrict__ x, float* __restrict__ mem,
                       float* __restrict__ states /* 8 * B*K floats */) {
    long long n = (long long)Bb * LL * KK;
    for (long long i = (long long)blockIdx.x * blockDim.x + threadIdx.x; i < n;
         i += (long long)gridDim.x * blockDim.x)
        mem[i] = x[i];
    for (int i = blockIdx.x * blockDim.x + threadIdx.x; i < 8 * Bb * KK;
         i += gridDim.x * blockDim.x)
        states[i] = 0.0f;
}

// ---------------- pre: Wf = cW @ wWx (512x1024), bf = cb @ wWx + wb ----------------
__global__ __launch_bounds__(256) void k_pre(
    const float* __restrict__ cW, const float* __restrict__ cb,
    const float* __restrict__ wWx, const float* __restrict__ wb,
    float* __restrict__ Wf, float* __restrict__ bf) {
    int tid = threadIdx.x;
    __shared__ float srow[N2K];
    if (blockIdx.x < N2K) {
        int kr = blockIdx.x;
        srow[tid] = cW[(size_t)kr * N2K + tid];
        srow[KK + tid] = cW[(size_t)kr * N2K + KK + tid];
        __syncthreads();
#pragma unroll
        for (int rep = 0; rep < 4; rep++) {
            int col = rep * 256 + tid;
            float a = 0.f;
#pragma unroll 4
            for (int c = 0; c < N2K; c++) a += srow[c] * wWx[(size_t)c * N4K + col];
            Wf[(size_t)kr * N4K + col] = a;
        }
    } else {
        int col = (blockIdx.x - N2K) * 256 + tid;
        float a = wb[col];
#pragma unroll 4
        for (int c = 0; c < N2K; c++) a += cb[c] * wWx[(size_t)c * N4K + col];
        bf[col] = a;
    }
}

// ---------------- reader LSTM block: 32 j x 4 gates (2 cols/thread), 4-way k-split ----
__device__ __forceinline__ void reader_blk(
    int b, int jg, int tid, int t1,
    const float* __restrict__ x, const float* __restrict__ rWx,
    const float* __restrict__ rWh, const float* __restrict__ rbv,
    const float* __restrict__ hr_in, const float* __restrict__ cr_in,
    float* __restrict__ hr_out, float* __restrict__ cr_out,
    float* shin /*512*/, float* sred /*512*/, float* sg /*128*/) {
    shin[tid] = x[((size_t)b * LL + t1) * KK + tid];
    shin[KK + tid] = hr_in[b * KK + tid];
    __syncthreads();
    int c64 = tid & 63, ks = tid >> 6;
    int g = c64 >> 4, jq = c64 & 15;
    int col = g * KK + jg * 32 + jq;   // and col+16
    float acc0 = (ks == 0) ? rbv[col] : 0.f;
    float acc1 = (ks == 0) ? rbv[col + 16] : 0.f;
    int k0 = ks * 128;
    const float* W = (ks < 2) ? (rWx + (size_t)k0 * N4K) : (rWh + (size_t)(k0 - KK) * N4K);
    for (int kk = 0; kk < 128; kk += 4) {
        const float* Wk = W + (size_t)kk * N4K + col;
        float4 v = *(const float4*)&shin[k0 + kk];
        acc0 += v.x * Wk[0]        + v.y * Wk[N4K]        + v.z * Wk[2 * N4K]        + v.w * Wk[3 * N4K];
        acc1 += v.x * Wk[16]       + v.y * Wk[N4K + 16]   + v.z * Wk[2 * N4K + 16]   + v.w * Wk[3 * N4K + 16];
    }
    sred[ks * 64 + c64] = acc0;
    sred[256 + ks * 64 + c64] = acc1;
    __syncthreads();
    if (tid < 128) {
        int p = tid >> 6, l = tid & 63;
        sg[p * 64 + l] = sred[p * 256 + l] + sred[p * 256 + 64 + l] +
                         sred[p * 256 + 128 + l] + sred[p * 256 + 192 + l];
    }
    __syncthreads();
    if (tid < 32) {
        int p = tid >> 4, jq2 = tid & 15;
        int j = jg * 32 + p * 16 + jq2;
        float gi = sg[p * 64 + jq2], gf = sg[p * 64 + 16 + jq2];
        float gG = sg[p * 64 + 32 + jq2], go = sg[p * 64 + 48 + jq2];
        float cn = sigf(gf) * cr_in[b * KK + j] + sigf(gi) * tanhf(gG);
        float hn = sigf(go) * tanhf(cn);
        cr_out[b * KK + j] = cn;
        hr_out[b * KK + j] = hn;
    }
}

__global__ __launch_bounds__(256) void k_rd(
    const float* __restrict__ x, const float* __restrict__ rWx,
    const float* __restrict__ rWh, const float* __restrict__ rbv,
    const float* __restrict__ hr_in, const float* __restrict__ cr_in,
    float* __restrict__ hr_out, float* __restrict__ cr_out, int t) {
    __shared__ float shin[N2K];
    __shared__ float sred[512];
    __shared__ float sg[128];
    reader_blk(blockIdx.x >> 3, blockIdx.x & 7, threadIdx.x, t, x, rWx, rWh, rbv,
               hr_in, cr_in, hr_out, cr_out, shin, sred, sg);
}

// ---------------- attention: (deferred mem update) + scores + online softmax ----------------
// grid (NC, B), 256 threads = 4 waves; wave handles 8 rows; lane holds K-slice [ln*4, ln*4+4)
__global__ __launch_bounds__(256) void k_attn(
    float* __restrict__ mem, const float* __restrict__ hr,
    float* __restrict__ s, float* __restrict__ partM, float* __restrict__ partS,
    float* __restrict__ partV, const float* __restrict__ hw_prev,
    const float* __restrict__ Mf, const float* __restrict__ Sf, int upd) {
    int c = blockIdx.x, b = blockIdx.y;
    int tid = threadIdx.x, w = tid >> 6, ln = tid & 63;

    float4 h4 = ((const float4*)(hr + b * KK))[ln];
    float4 w4 = make_float4(0.f, 0.f, 0.f, 0.f);
    float Mprev = 0.f, invS = 0.f;
    if (upd) {
        w4 = ((const float4*)(hw_prev + b * KK))[ln];
        Mprev = Mf[b];
        invS = 1.0f / Sf[b];
    }

    float Mw = -INFINITY, Sw = 0.f;
    float4 Vw = make_float4(0.f, 0.f, 0.f, 0.f);
    int l0 = c * RC + w * 8;
#pragma unroll
    for (int i = 0; i < 8; i++) {
        int l = l0 + i;
        float4* vp = (float4*)(mem + ((size_t)(b * LL + l)) * KK) + ln;
        float4 v = *vp;
        if (upd) {
            float z = __expf(s[b * LL + l] - Mprev) * invS;
            float om = 1.0f - z;
            v.x = v.x * om + w4.x * z;
            v.y = v.y * om + w4.y * z;
            v.z = v.z * om + w4.z * z;
            v.w = v.w * om + w4.w * z;
            *vp = v;
        }
        float d = h4.x * v.x + h4.y * v.y + h4.z * v.z + h4.w * v.w;
#pragma unroll
        for (int m = 1; m < 64; m <<= 1) d += __shfl_xor(d, m, 64);
        if (ln == 0) s[b * LL + l] = d;
        float nM = fmaxf(Mw, d);
        float sc = __expf(Mw - nM);
        float e = __expf(d - nM);
        Sw = Sw * sc + e;
        Vw.x = Vw.x * sc + e * v.x;
        Vw.y = Vw.y * sc + e * v.y;
        Vw.z = Vw.z * sc + e * v.z;
        Vw.w = Vw.w * sc + e * v.w;
        Mw = nM;
    }
    __shared__ float sM4[4], sS4[4];
    __shared__ float sV[4][KK];
    sV[w][ln * 4 + 0] = Vw.x;
    sV[w][ln * 4 + 1] = Vw.y;
    sV[w][ln * 4 + 2] = Vw.z;
    sV[w][ln * 4 + 3] = Vw.w;
    if (ln == 0) { sM4[w] = Mw; sS4[w] = Sw; }
    __syncthreads();
    int k = tid;
    float M = fmaxf(fmaxf(sM4[0], sM4[1]), fmaxf(sM4[2], sM4[3]));
    float e0 = __expf(sM4[0] - M), e1 = __expf(sM4[1] - M);
    float e2 = __expf(sM4[2] - M), e3 = __expf(sM4[3] - M);
    float S = e0 * sS4[0] + e1 * sS4[1] + e2 * sS4[2] + e3 * sS4[3];
    float V = e0 * sV[0][k] + e1 * sV[1][k] + e2 * sV[2][k] + e3 * sV[3][k];
    partV[((size_t)(b * NC + c)) * KK + k] = V;
    if (tid == 0) {
        partM[b * NC + c] = M;
        partS[b * NC + c] = S;
    }
}

// ---------------- fused writer (blocks 0..255) + reader t+1 (blocks 256..511) -------
// writer block (b, jg): jg in [0,8) covers 32 j-outputs (2 cols/thread), 4-way k-split
// over 768 rows: [hr(256)|m_rt(256)]@Wf + hw@wWh, + bf.
__global__ __launch_bounds__(256) void k_wrf(
    const float* __restrict__ partM, const float* __restrict__ partS,
    const float* __restrict__ partV, const float* __restrict__ hr_cur,
    const float* __restrict__ Wf, const float* __restrict__ bf,
    const float* __restrict__ wWh,
    const float* __restrict__ hw_in, const float* __restrict__ cw_in,
    float* __restrict__ hw_out, float* __restrict__ cw_out,
    float* __restrict__ Mf, float* __restrict__ Sf, float* __restrict__ out, int t,
    const float* __restrict__ x, const float* __restrict__ rWx,
    const float* __restrict__ rWh, const float* __restrict__ rbv,
    const float* __restrict__ hr_in, const float* __restrict__ cr_in,
    float* __restrict__ hr_out, float* __restrict__ cr_out, int do_reader) {
    __shared__ float shin[768];
    __shared__ float sred[512];
    __shared__ float sg[128];
    __shared__ float sMp[NC], sSp[NC], sEp[NC];
    int tid = threadIdx.x;
    if (blockIdx.x < 256) {
        int b = blockIdx.x >> 3, jg = blockIdx.x & 7;
        if (tid < NC) {
            sMp[tid] = partM[b * NC + tid];
            sSp[tid] = partS[b * NC + tid];
        }
        __syncthreads();
        float M = -INFINITY;
#pragma unroll
        for (int c2 = 0; c2 < NC; c2++) M = fmaxf(M, sMp[c2]);
        if (tid < NC) sEp[tid] = __expf(sMp[tid] - M);
        __syncthreads();
        float S = 0.f;
#pragma unroll
        for (int c2 = 0; c2 < NC; c2++) S += sEp[c2] * sSp[c2];
        float V = 0.f;
        for (int c2 = 0; c2 < NC; c2++) V += sEp[c2] * partV[((size_t)(b * NC + c2)) * KK + tid];
        shin[tid] = hr_cur[b * KK + tid];
        shin[KK + tid] = V / S;
        shin[N2K + tid] = hw_in[b * KK + tid];
        if (jg == 0 && tid == 0) { Mf[b] = M; Sf[b] = S; }
        __syncthreads();
        int c64 = tid & 63, ks = tid >> 6;
        int g = c64 >> 4, jq = c64 & 15;
        int col = g * KK + jg * 32 + jq;   // and col+16
        float acc0 = (ks == 0) ? bf[col] : 0.f;
        float acc1 = (ks == 0) ? bf[col + 16] : 0.f;
        int k0 = ks * 192, k1 = k0 + 192;
        int kb = k1 < N2K ? k1 : N2K;
        for (int k = k0; k < kb; k += 4) {
            const float* Wk = Wf + (size_t)k * N4K + col;
            float4 v = *(const float4*)&shin[k];
            acc0 += v.x * Wk[0]      + v.y * Wk[N4K]      + v.z * Wk[2 * N4K]      + v.w * Wk[3 * N4K];
            acc1 += v.x * Wk[16]     + v.y * Wk[N4K + 16] + v.z * Wk[2 * N4K + 16] + v.w * Wk[3 * N4K + 16];
        }
        for (int k = (k0 > N2K ? k0 : N2K); k < k1; k += 4) {
            const float* Wk = wWh + (size_t)(k - N2K) * N4K + col;
            float4 v = *(const float4*)&shin[k];
            acc0 += v.x * Wk[0]      + v.y * Wk[N4K]      + v.z * Wk[2 * N4K]      + v.w * Wk[3 * N4K];
            acc1 += v.x * Wk[16]     + v.y * Wk[N4K + 16] + v.z * Wk[2 * N4K + 16] + v.w * Wk[3 * N4K + 16];
        }
        sred[ks * 64 + c64] = acc0;
        sred[256 + ks * 64 + c64] = acc1;
        __syncthreads();
        if (tid < 128) {
            int p = tid >> 6, l = tid & 63;
            sg[p * 64 + l] = sred[p * 256 + l] + sred[p * 256 + 64 + l] +
                             sred[p * 256 + 128 + l] + sred[p * 256 + 192 + l];
        }
        __syncthreads();
        if (tid < 32) {
            int p = tid >> 4, jq2 = tid & 15;
            int j = jg * 32 + p * 16 + jq2;
            float gi = sg[p * 64 + jq2], gf = sg[p * 64 + 16 + jq2];
            float gG = sg[p * 64 + 32 + jq2], go = sg[p * 64 + 48 + jq2];
            float cn = sigf(gf) * cw_in[b * KK + j] + sigf(gi) * tanhf(gG);
            float hn = sigf(go) * tanhf(cn);
            cw_out[b * KK + j] = cn;
            hw_out[b * KK + j] = hn;
            out[((size_t)b * LL + t) * KK + j] = hn;
        }
    } else if (do_reader) {
        int r2 = blockIdx.x - 256;
        reader_blk(r2 >> 3, r2 & 7, tid, t + 1, x, rWx, rWh, rbv,
                   hr_in, cr_in, hr_out, cr_out, shin, sred, sg);
    }
}

// ---------------- host ----------------
extern "C" void kernel_launch(void* const* d_in, const int* in_sizes, int n_in,
                              void* d_out, int out_size, void* d_ws, size_t ws_size,
                              hipStream_t stream) {
    const float* x   = (const float*)d_in[0];
    const float* rWx = (const float*)d_in[1];
    const float* rWh = (const float*)d_in[2];
    const float* rb  = (const float*)d_in[3];
    const float* wWx = (const float*)d_in[4];
    const float* wWh = (const float*)d_in[5];
    const float* wb  = (const float*)d_in[6];
    const float* cW  = (const float*)d_in[7];
    const float* cb  = (const float*)d_in[8];
    float* out = (float*)d_out;

    float* ws = (float*)d_ws;
    const size_t MEM = (size_t)Bb * LL * KK;  // 8388608
    float* mem = ws;
    float* states = ws + MEM;                 // 8 state buffers, contiguous
    float* hr[2] = {states + 0 * Bb * KK, states + 1 * Bb * KK};
    float* cr[2] = {states + 2 * Bb * KK, states + 3 * Bb * KK};
    float* hw[2] = {states + 4 * Bb * KK, states + 5 * Bb * KK};
    float* cw[2] = {states + 6 * Bb * KK, states + 7 * Bb * KK};
    float* s     = states + 8 * Bb * KK;              // B*L
    float* partM = s + (size_t)Bb * LL;               // B*NC
    float* partS = partM + Bb * NC;                   // B*NC
    float* partV = partS + Bb * NC;                   // B*NC*K
    float* Mf    = partV + (size_t)Bb * NC * KK;      // B
    float* Sf    = Mf + Bb;                           // B
    float* Wf    = Sf + Bb;                           // 512*1024
    float* bf    = Wf + (size_t)N2K * N4K;            // 1024

    k_init<<<4096, 256, 0, stream>>>(x, mem, states);
    k_pre<<<516, 256, 0, stream>>>(cW, cb, wWx, wb, Wf, bf);
    k_rd<<<256, 256, 0, stream>>>(x, rWx, rWh, rb, hr[0], cr[0], hr[1], cr[1], 0);

    for (int t = 0; t < LL; t++) {
        int pi = t & 1;
        int po = (t + 1) & 1;
        k_attn<<<dim3(NC, Bb), 256, 0, stream>>>(mem, hr[po], s, partM, partS, partV,
                                                 hw[pi], Mf, Sf, t > 0 ? 1 : 0);
        k_wrf<<<512, 256, 0, stream>>>(partM, partS, partV, hr[po], Wf, bf, wWh,
                                       hw[pi], cw[pi], hw[po], cw[po], Mf, Sf, out, t,
                                       x, rWx, rWh, rb, hr[po], cr[po], hr[pi], cr[pi],
                                       (t + 1 < LL) ? 1 : 0);
    }
}